// Round 8
// baseline (565.537 us; speedup 1.0000x reference)
//
#include <hip/hip_runtime.h>
#include <cstddef>
#include <cstdint>

constexpr int IN_F  = 128;
constexpr int HID_F = 256;
constexpr int EMB_F = 64;

typedef float  f32x4  __attribute__((ext_vector_type(4)));
typedef short  bf16x8 __attribute__((ext_vector_type(8)));
typedef unsigned short ushort_t;
typedef ushort_t u16x8 __attribute__((ext_vector_type(8)));
typedef ushort_t u16x4 __attribute__((ext_vector_type(4)));

__device__ inline float bf2f(ushort_t u) {
  union { unsigned i; float f; } c; c.i = ((unsigned)u) << 16; return c.f;
}
__device__ inline ushort_t f2bf(float f) {  // round-to-nearest-even
  union { float f; unsigned i; } c; c.f = f;
  unsigned r = c.i + 0x7FFFu + ((c.i >> 16) & 1u);
  return (ushort_t)(r >> 16);
}

constexpr int NBKT = 512;       // bucket array size; used = ceil(N/256)
constexpr int CHUNK = 16384;    // edges per block in hist/passA

// ---------------- setup: weight transposes to bf16 + ghist zero ----------------

__global__ void k_setup(const float* __restrict__ W1, const float* __restrict__ W2,
                        const float* __restrict__ W3,
                        ushort_t* __restrict__ W1t, ushort_t* __restrict__ W2t,
                        ushort_t* __restrict__ W3t, int* __restrict__ ghist) {
  constexpr int c1 = IN_F * HID_F;
  constexpr int c2 = c1 + HID_F * HID_F;
  constexpr int c3 = c2 + HID_F * EMB_F;
  int i = blockIdx.x * blockDim.x + threadIdx.x;
  if (i < c1) {
    int k = i / HID_F, nn = i - k * HID_F;
    W1t[(size_t)nn * IN_F + k] = f2bf(W1[i]);
  } else if (i < c2) {
    int j = i - c1;
    int k = j / HID_F, nn = j - k * HID_F;
    W2t[(size_t)nn * HID_F + k] = f2bf(W2[j]);
  } else if (i < c3) {
    int j = i - c2;
    int k = j / EMB_F, nn = j - k * EMB_F;
    W3t[(size_t)nn * HID_F + k] = f2bf(W3[j]);
  } else if (i - c3 < NBKT) {
    ghist[i - c3] = 0;
  }
}

// ---------------- bucketed CSR build ----------------
// bucket = dst >> 8; pack = ((dst&255)<<17) | src  (src < 2^17)

__global__ __launch_bounds__(512) void k_hist(const int* __restrict__ dst,
                                              int* __restrict__ ghist, int e) {
  __shared__ int cnt[NBKT];
  cnt[threadIdx.x] = 0;
  __syncthreads();
  int i0 = blockIdx.x * CHUNK;
  int i1 = min(e, i0 + CHUNK);
  for (int i = i0 + threadIdx.x; i < i1; i += 512)
    atomicAdd(&cnt[dst[i] >> 8], 1);
  __syncthreads();
  int c = cnt[threadIdx.x];
  if (c > 0) atomicAdd(&ghist[threadIdx.x], c);
}

// exclusive scan of ghist -> bstart (== global rowptr at bucket starts); gcursor = bstart
__global__ __launch_bounds__(512) void k_bscan(const int* __restrict__ ghist,
                                               int* __restrict__ bstart,
                                               int* __restrict__ gcursor) {
  __shared__ int s[NBKT];
  int v = ghist[threadIdx.x];
  s[threadIdx.x] = v;
  __syncthreads();
#pragma unroll
  for (int off = 1; off < NBKT; off <<= 1) {
    int t = (threadIdx.x >= off) ? s[threadIdx.x - off] : 0;
    __syncthreads();
    s[threadIdx.x] += t;
    __syncthreads();
  }
  int ex = s[threadIdx.x] - v;
  bstart[threadIdx.x] = ex;
  gcursor[threadIdx.x] = ex;
}

__global__ __launch_bounds__(512) void k_passA(const int* __restrict__ src,
                                               const int* __restrict__ dst,
                                               int* __restrict__ gcursor,
                                               unsigned* __restrict__ staged, int e) {
  __shared__ int cnt[NBKT];
  __shared__ int base[NBKT];
  cnt[threadIdx.x] = 0;
  __syncthreads();
  int i0 = blockIdx.x * CHUNK;
  int i1 = min(e, i0 + CHUNK);
  for (int i = i0 + threadIdx.x; i < i1; i += 512)
    atomicAdd(&cnt[dst[i] >> 8], 1);
  __syncthreads();
  int c = cnt[threadIdx.x];
  base[threadIdx.x] = (c > 0) ? atomicAdd(&gcursor[threadIdx.x], c) : 0;
  cnt[threadIdx.x] = 0;  // reuse as local cursor
  __syncthreads();
  for (int i = i0 + threadIdx.x; i < i1; i += 512) {
    int d = dst[i];
    int b = d >> 8;
    int lp = atomicAdd(&cnt[b], 1);
    staged[base[b] + lp] = ((unsigned)(d & 255) << 17) | (unsigned)src[i];
  }
}

// Fused per-bucket finalize: count -> dinv + rowptr (bstart[b] + local scan),
// place csr via LDS cursors, convert this bucket's x rows to pre-scaled bf16.
__global__ __launch_bounds__(256) void k_Bfused(
    const unsigned* __restrict__ staged, const int* __restrict__ bstart,
    const int* __restrict__ ghist, const float* __restrict__ x,
    float* __restrict__ dinv, int* __restrict__ rowptr, int* __restrict__ csr,
    ushort_t* __restrict__ xb, int n, int e) {
  __shared__ int cnt[256];
  __shared__ int s[256];
  __shared__ int cur[256];
  __shared__ float dinvL[256];
  const int tid = threadIdx.x;
  const int b = blockIdx.x;
  cnt[tid] = 0;
  __syncthreads();
  const int beg = bstart[b], end = beg + ghist[b];
  for (int i = beg + tid; i < end; i += 256)
    atomicAdd(&cnt[staged[i] >> 17], 1);
  __syncthreads();
  const int node = (b << 8) + tid;
  int v = (node < n) ? cnt[tid] : 0;
  float dv = rsqrtf((float)(v + 1));
  if (node < n) { dinv[node] = dv; }
  dinvL[tid] = dv;
  s[tid] = v;
  __syncthreads();
#pragma unroll
  for (int off = 1; off < 256; off <<= 1) {
    int t = (tid >= off) ? s[tid - off] : 0;
    __syncthreads();
    s[tid] += t;
    __syncthreads();
  }
  int rp = beg + s[tid] - v;  // global rowptr for this node
  if (node < n) rowptr[node] = rp;
  if (b == 0 && tid == 0) rowptr[n] = e;
  cur[tid] = rp;
  __syncthreads();
  // place edges
  for (int i = beg + tid; i < end; i += 256) {
    unsigned p = staged[i];
    int l = (int)(p >> 17);
    int sv = (int)(p & 0x1FFFFu);
    int pos = atomicAdd(&cur[l], 1);
    csr[pos] = sv;
  }
  // xconv for this bucket's nodes: 256 rows x 32 float4
  const int nb0 = b << 8;
  const int rows = min(256, n - nb0);
  const float4* xv = reinterpret_cast<const float4*>(x) + (size_t)nb0 * 32;
  u16x4* xo = reinterpret_cast<u16x4*>(xb) + (size_t)nb0 * 32;
  for (int j = tid; j < rows * 32; j += 256) {
    float sc = dinvL[j >> 5];
    float4 vv = xv[j];
    u16x4 o;
    o[0] = f2bf(vv.x * sc); o[1] = f2bf(vv.y * sc);
    o[2] = f2bf(vv.z * sc); o[3] = f2bf(vv.w * sc);
    xo[j] = o;
  }
}

// ---------------- block GEMM, LDS A-staging (64 rows x 256 cols / block) ----------------
// C[M][256] = dinv[row] * ((GATHER ? A_hat*A : A)[M][K] @ Wt[256][K]^T) (+bias,relu)
// 4 waves; wave w computes cols [w*64, w*64+64). A staged once in LDS with
// chunk-XOR swizzle (chunk ^= row&7, 16B chunks) -> ~2-way-free ds_read_b128.
// mfma_f32_16x16x32_bf16; C/D: col=lane&15, row=(lane>>4)*4+reg (m89-verified).

template<int K, bool RELU, bool GATHER>
__global__ __launch_bounds__(256) void k_gemm_big(
    const ushort_t* __restrict__ A, const ushort_t* __restrict__ Wt,
    ushort_t* __restrict__ C, const float* __restrict__ dinv,
    const float* __restrict__ bias, const int* __restrict__ rowptr,
    const int* __restrict__ csr, int M) {
  __shared__ ushort_t As[64 * K];
  const int tid = threadIdx.x;
  const int lane = tid & 63;
  const int w = tid >> 6;
  const int mbase = blockIdx.x * 64;

  if constexpr (GATHER) {
    // wave w aggregates rows [w*16, w*16+16): lane-split gather (2 item-groups)
    const int half = lane >> 5, sub = lane & 31;
    const int coff = sub * 4;  // bf16 col 0..124
    for (int rr = 0; rr < 16; ++rr) {
      const int r = w * 16 + rr;
      const int g = mbase + r;
      float acc[4] = {};
      if (g < M) {
        int beg = rowptr[g], end = rowptr[g + 1];
        int nitems = end - beg + 1;  // item 0 = self
        int i = 0;
        for (; i + 3 < nitems; i += 4) {
          int i0 = i + half, i1 = i + 2 + half;
          int r0 = (i0 == 0) ? g : csr[beg + i0 - 1];
          int r1 = csr[beg + i1 - 1];
          u16x4 v0 = *reinterpret_cast<const u16x4*>(A + (size_t)r0 * K + coff);
          u16x4 v1 = *reinterpret_cast<const u16x4*>(A + (size_t)r1 * K + coff);
#pragma unroll
          for (int k = 0; k < 4; ++k) acc[k] += bf2f(v0[k]);
#pragma unroll
          for (int k = 0; k < 4; ++k) acc[k] += bf2f(v1[k]);
        }
        for (; i < nitems; i += 2) {
          int i0 = i + half;
          if (i0 < nitems) {
            int r0 = (i0 == 0) ? g : csr[beg + i0 - 1];
            u16x4 v0 = *reinterpret_cast<const u16x4*>(A + (size_t)r0 * K + coff);
#pragma unroll
            for (int k = 0; k < 4; ++k) acc[k] += bf2f(v0[k]);
          }
        }
      }
#pragma unroll
      for (int k = 0; k < 4; ++k) acc[k] += __shfl_xor(acc[k], 32);
      if (half == 0) {
        int c = sub >> 1;                       // 16B chunk index 0..15
        int idx = r * K + ((c ^ (r & 7)) << 3) + (sub & 1) * 4;
        u16x4 o;
#pragma unroll
        for (int k = 0; k < 4; ++k) o[k] = f2bf(acc[k]);
        *reinterpret_cast<u16x4*>(&As[idx]) = o;
      }
    }
  } else {
    constexpr int CH = K / 8;  // 16B chunks per row
    for (int i = tid; i < 64 * CH; i += 256) {
      int row = i / CH, c = i - row * CH;
      int g = mbase + row;
      if (g >= M) g = M - 1;  // clamp; stores guarded
      u16x8 v = *reinterpret_cast<const u16x8*>(A + (size_t)g * K + c * 8);
      *reinterpret_cast<u16x8*>(&As[row * K + ((c ^ (row & 7)) << 3)]) = v;
    }
  }
  __syncthreads();

  const int lrow = lane & 15;
  const int lk = (lane >> 4) * 8;
  const int nbase = w * 64;
  f32x4 acc[4][4] = {};

#pragma unroll
  for (int k0 = 0; k0 < K; k0 += 32) {
    bf16x8 a[4], b[4];
    const int cbase = (k0 >> 3) + (lane >> 4);
#pragma unroll
    for (int i = 0; i < 4; ++i) {
      int ri = i * 16 + lrow;
      a[i] = *reinterpret_cast<const bf16x8*>(&As[ri * K + ((cbase ^ (ri & 7)) << 3)]);
    }
#pragma unroll
    for (int n = 0; n < 4; ++n)
      b[n] = *reinterpret_cast<const bf16x8*>(Wt + (size_t)(nbase + n * 16 + lrow) * K + k0 + lk);
#pragma unroll
    for (int i = 0; i < 4; ++i)
#pragma unroll
      for (int n = 0; n < 4; ++n)
        acc[i][n] = __builtin_amdgcn_mfma_f32_16x16x32_bf16(a[i], b[n], acc[i][n], 0, 0, 0);
  }

#pragma unroll
  for (int i = 0; i < 4; ++i) {
    int growb = mbase + i * 16 + (lane >> 4) * 4;
#pragma unroll
    for (int r = 0; r < 4; ++r) {
      int grow = growb + r;
      if (grow >= M) continue;
      float s = dinv[grow];
#pragma unroll
      for (int n = 0; n < 4; ++n) {
        int gcol = nbase + n * 16 + (lane & 15);
        float v = acc[i][n][r] * s;
        if (RELU) v = fmaxf(v + bias[gcol], 0.f);
        C[(size_t)grow * HID_F + gcol] = f2bf(v);
      }
    }
  }
}

// ---------------- gathers (unchanged structure) ----------------

// layer 2: F=256, row=512B = 32 lanes x 16B; 2 items/step, 2-unroll
__global__ __launch_bounds__(256) void k_gather2(
    const ushort_t* __restrict__ t, ushort_t* __restrict__ outp,
    const int* __restrict__ rowptr, const int* __restrict__ csr,
    const float* __restrict__ dinv, const float* __restrict__ bias, int n) {
  int wid = (blockIdx.x * blockDim.x + threadIdx.x) >> 6;
  int lane = threadIdx.x & 63;
  if (wid >= n) return;
  const int half = lane >> 5, sub = lane & 31;
  const int coff = sub * 8;
  int beg = rowptr[wid], end = rowptr[wid + 1];
  int nitems = end - beg + 1;
  float acc[8] = {};
  int i = 0;
  for (; i + 3 < nitems; i += 4) {
    int i0 = i + half, i1 = i + 2 + half;
    int r0 = (i0 == 0) ? wid : csr[beg + i0 - 1];
    int r1 = csr[beg + i1 - 1];
    u16x8 v0 = *reinterpret_cast<const u16x8*>(t + (size_t)r0 * HID_F + coff);
    u16x8 v1 = *reinterpret_cast<const u16x8*>(t + (size_t)r1 * HID_F + coff);
#pragma unroll
    for (int k = 0; k < 8; ++k) acc[k] += bf2f(v0[k]);
#pragma unroll
    for (int k = 0; k < 8; ++k) acc[k] += bf2f(v1[k]);
  }
  for (; i < nitems; i += 2) {
    int i0 = i + half;
    if (i0 < nitems) {
      int r0 = (i0 == 0) ? wid : csr[beg + i0 - 1];
      u16x8 v0 = *reinterpret_cast<const u16x8*>(t + (size_t)r0 * HID_F + coff);
#pragma unroll
      for (int k = 0; k < 8; ++k) acc[k] += bf2f(v0[k]);
    }
  }
#pragma unroll
  for (int k = 0; k < 8; ++k) acc[k] += __shfl_xor(acc[k], 32);
  if (half == 0) {
    float s = dinv[wid];
    u16x8 o;
#pragma unroll
    for (int k = 0; k < 8; ++k) o[k] = f2bf(fmaxf(fmaf(acc[k], s, bias[coff + k]), 0.f));
    *reinterpret_cast<u16x8*>(outp + (size_t)wid * HID_F + coff) = o;
  }
}

// layer 3: F=64, row=128B = 16 lanes x 8B; 4 items/step; bias + L2-normalize
__global__ __launch_bounds__(256) void k_gather3(
    const ushort_t* __restrict__ t, float* __restrict__ outp,
    const int* __restrict__ rowptr, const int* __restrict__ csr,
    const float* __restrict__ dinv, const float* __restrict__ b3, int n) {
  int wid = (blockIdx.x * blockDim.x + threadIdx.x) >> 6;
  int lane = threadIdx.x & 63;
  if (wid >= n) return;
  const int q = lane >> 4, sub = lane & 15;
  const int coff = sub * 4;
  int beg = rowptr[wid], end = rowptr[wid + 1];
  int nitems = end - beg + 1;
  float acc[4] = {};
  for (int i = 0; i < nitems; i += 4) {
    int i0 = i + q;
    if (i0 < nitems) {
      int r0 = (i0 == 0) ? wid : csr[beg + i0 - 1];
      u16x4 v0 = *reinterpret_cast<const u16x4*>(t + (size_t)r0 * EMB_F + coff);
#pragma unroll
      for (int k = 0; k < 4; ++k) acc[k] += bf2f(v0[k]);
    }
  }
#pragma unroll
  for (int k = 0; k < 4; ++k) acc[k] += __shfl_xor(acc[k], 16);
#pragma unroll
  for (int k = 0; k < 4; ++k) acc[k] += __shfl_xor(acc[k], 32);
  float s = dinv[wid];
  float v[4], ss = 0.f;
#pragma unroll
  for (int k = 0; k < 4; ++k) {
    v[k] = fmaf(acc[k], s, b3[coff + k]);
    ss = fmaf(v[k], v[k], ss);
  }
#pragma unroll
  for (int off = 8; off > 0; off >>= 1) ss += __shfl_xor(ss, off);
  float inv = 1.0f / fmaxf(sqrtf(ss), 1e-12f);
  if (lane < 16) {
    float4 o = make_float4(v[0] * inv, v[1] * inv, v[2] * inv, v[3] * inv);
    *reinterpret_cast<float4*>(outp + (size_t)wid * EMB_F + coff) = o;
  }
}

// ---------------- LDS-free wave GEMM (layer 3: N=64, A read once) ----------------

template<int K, bool RELU>
__global__ __launch_bounds__(256) void k_mfma_gemm(
    const ushort_t* __restrict__ A, const ushort_t* __restrict__ Wt,
    ushort_t* __restrict__ C,
    const float* __restrict__ dinv, const float* __restrict__ bias,
    int M, int NT /* N/64 */) {
  int w = blockIdx.x * 4 + (threadIdx.x >> 6);
  int lane = threadIdx.x & 63;
  int mt = w / NT, nt = w - mt * NT;
  int mbase = mt * 64, nbase = nt * 64;
  if (mbase >= M) return;
  const int lrow = lane & 15;
  const int lk = (lane >> 4) * 8;
  const int N = NT * 64;

  int rows[4];
#pragma unroll
  for (int i = 0; i < 4; ++i) {
    int r = mbase + i * 16 + lrow;
    rows[i] = (r < M) ? r : (M - 1);  // clamp loads; stores guarded
  }

  f32x4 acc[4][4] = {};

#pragma unroll 2
  for (int k0 = 0; k0 < K; k0 += 32) {
    bf16x8 a[4], b[4];
#pragma unroll
    for (int i = 0; i < 4; ++i)
      a[i] = *reinterpret_cast<const bf16x8*>(A + (size_t)rows[i] * K + k0 + lk);
#pragma unroll
    for (int n = 0; n < 4; ++n)
      b[n] = *reinterpret_cast<const bf16x8*>(Wt + (size_t)(nbase + n * 16 + lrow) * K + k0 + lk);
#pragma unroll
    for (int i = 0; i < 4; ++i)
#pragma unroll
      for (int n = 0; n < 4; ++n)
        acc[i][n] = __builtin_amdgcn_mfma_f32_16x16x32_bf16(a[i], b[n], acc[i][n], 0, 0, 0);
  }

#pragma unroll
  for (int i = 0; i < 4; ++i) {
    int growb = mbase + i * 16 + (lane >> 4) * 4;
#pragma unroll
    for (int r = 0; r < 4; ++r) {
      int grow = growb + r;
      if (grow >= M) continue;
      float s = dinv[grow];
#pragma unroll
      for (int n = 0; n < 4; ++n) {
        int gcol = nbase + n * 16 + (lane & 15);
        float v = acc[i][n][r] * s;
        if (RELU) v = fmaxf(v + bias[gcol], 0.f);
        C[(size_t)grow * N + gcol] = f2bf(v);
      }
    }
  }
}

// ---------------- launch ----------------

extern "C" void kernel_launch(void* const* d_in, const int* in_sizes, int n_in,
                              void* d_out, int out_size, void* d_ws, size_t ws_size,
                              hipStream_t stream) {
  const float* x  = (const float*)d_in[0];
  const int*   ei = (const int*)d_in[1];
  const float* W1 = (const float*)d_in[2];
  const float* b1 = (const float*)d_in[3];
  const float* W2 = (const float*)d_in[4];
  const float* b2 = (const float*)d_in[5];
  const float* W3 = (const float*)d_in[6];
  const float* b3 = (const float*)d_in[7];
  const int N = in_sizes[0] / IN_F;
  const int E = in_sizes[1] / 2;
  const int* src = ei;
  const int* dst = ei + E;

  char* m = (char*)d_ws;
  auto alloc = [&](size_t bytes) { char* p = m; m += (bytes + 255) & ~(size_t)255; return p; };
  ushort_t* U1  = (ushort_t*)alloc((size_t)N * HID_F * 2);  // N x 256 bf16
  ushort_t* U2  = (ushort_t*)alloc((size_t)N * HID_F * 2);
  ushort_t* W1t = (ushort_t*)alloc((size_t)IN_F * HID_F * 2);
  ushort_t* W2t = (ushort_t*)alloc((size_t)HID_F * HID_F * 2);
  ushort_t* W3t = (ushort_t*)alloc((size_t)HID_F * EMB_F * 2);
  float*    dinv    = (float*)alloc((size_t)N * 4);
  int*      rowptr  = (int*)alloc((size_t)(N + 1) * 4);
  int*      ghist   = (int*)alloc(NBKT * 4);
  int*      bstart  = (int*)alloc(NBKT * 4);
  int*      gcursor = (int*)alloc(NBKT * 4);
  unsigned* staged  = (unsigned*)alloc((size_t)E * 4);
  int*      csr     = (int*)alloc((size_t)E * 4);
  float*    out     = (float*)d_out;

  const int nb = (N + 255) / 256;        // buckets (<= NBKT)
  const int echunks = (E + CHUNK - 1) / CHUNK;
  constexpr int SETUP_W = IN_F * HID_F + HID_F * HID_F + HID_F * EMB_F + NBKT;

  // weights -> bf16 transposed; ghist = 0
  k_setup<<<(SETUP_W + 255) / 256, 256, 0, stream>>>(W1, W2, W3, W1t, W2t, W3t, ghist);

  // bucketed CSR build
  k_hist  <<<echunks, 512, 0, stream>>>(dst, ghist, E);
  k_bscan <<<1, NBKT, 0, stream>>>(ghist, bstart, gcursor);
  k_passA <<<echunks, 512, 0, stream>>>(src, dst, gcursor, staged, E);

  // fused: dinv + rowptr + csr placement + xb = bf16(x * dinv)   (xb aliased into U2)
  ushort_t* xb = U2;
  k_Bfused<<<nb, 256, 0, stream>>>(staged, bstart, ghist, x, dinv, rowptr, csr, xb, N, E);

  const int gblocks = (N + 3) / 4;  // gather2/3: 4 waves per block, 1 node per wave
  const int MT = (N + 63) / 64;

  // layer 1 (fused): gather xb + GEMM 128->256 (+dinv row, +b1, relu) -> h1
  ushort_t* h1 = U1;
  k_gemm_big<IN_F, true, true><<<MT, 256, 0, stream>>>(
      xb, W1t, h1, dinv, b1, rowptr, csr, N);

  // layer 2: GEMM 256->256 (dinv row) -> t2 (xb dead); gather (+dinv, b2, relu) -> h2
  ushort_t* t2 = U2;
  k_gemm_big<HID_F, false, false><<<MT, 256, 0, stream>>>(
      h1, W2t, t2, dinv, nullptr, nullptr, nullptr, N);
  ushort_t* h2 = U1;
  k_gather2<<<gblocks, 256, 0, stream>>>(t2, h2, rowptr, csr, dinv, b2, N);

  // layer 3: GEMM 256->64 (dinv row) -> t3; gather (+dinv, b3) + L2-normalize -> out
  ushort_t* t3 = U2;
  k_mfma_gemm<HID_F, false><<<(MT * (EMB_F / 64) + 3) / 4, 256, 0, stream>>>(
      h2, W3t, t3, dinv, nullptr, N, EMB_F / 64);
  k_gather3<<<gblocks, 256, 0, stream>>>(t3, out, rowptr, csr, dinv, b3, N);
}

// Round 9
// 435.829 us; speedup vs baseline: 1.2976x; 1.2976x over previous
//
#include <hip/hip_runtime.h>
#include <cstddef>
#include <cstdint>

constexpr int IN_F  = 128;
constexpr int HID_F = 256;
constexpr int EMB_F = 64;

typedef float  f32x4  __attribute__((ext_vector_type(4)));
typedef short  bf16x8 __attribute__((ext_vector_type(8)));
typedef unsigned short ushort_t;
typedef ushort_t u16x8 __attribute__((ext_vector_type(8)));
typedef ushort_t u16x4 __attribute__((ext_vector_type(4)));

__device__ inline float bf2f(ushort_t u) {
  union { unsigned i; float f; } c; c.i = ((unsigned)u) << 16; return c.f;
}
__device__ inline ushort_t f2bf(float f) {  // round-to-nearest-even
  union { float f; unsigned i; } c; c.f = f;
  unsigned r = c.i + 0x7FFFu + ((c.i >> 16) & 1u);
  return (ushort_t)(r >> 16);
}

constexpr int NBKT = 512;       // bucket array size; used = ceil(N/256)
constexpr int CHUNK = 16384;    // edges per block in hist/passA

// ---------------- setup: weight transposes to bf16 + ghist zero ----------------

__global__ void k_setup(const float* __restrict__ W1, const float* __restrict__ W2,
                        const float* __restrict__ W3,
                        ushort_t* __restrict__ W1t, ushort_t* __restrict__ W2t,
                        ushort_t* __restrict__ W3t, int* __restrict__ ghist) {
  constexpr int c1 = IN_F * HID_F;
  constexpr int c2 = c1 + HID_F * HID_F;
  constexpr int c3 = c2 + HID_F * EMB_F;
  int i = blockIdx.x * blockDim.x + threadIdx.x;
  if (i < c1) {
    int k = i / HID_F, nn = i - k * HID_F;
    W1t[(size_t)nn * IN_F + k] = f2bf(W1[i]);
  } else if (i < c2) {
    int j = i - c1;
    int k = j / HID_F, nn = j - k * HID_F;
    W2t[(size_t)nn * HID_F + k] = f2bf(W2[j]);
  } else if (i < c3) {
    int j = i - c2;
    int k = j / EMB_F, nn = j - k * EMB_F;
    W3t[(size_t)nn * HID_F + k] = f2bf(W3[j]);
  } else if (i - c3 < NBKT) {
    ghist[i - c3] = 0;
  }
}

// ---------------- bucketed CSR build ----------------
// bucket = dst >> 8; pack = ((dst&255)<<17) | src  (src < 2^17)

__global__ __launch_bounds__(512) void k_hist(const int* __restrict__ dst,
                                              int* __restrict__ ghist, int e) {
  __shared__ int cnt[NBKT];
  cnt[threadIdx.x] = 0;
  __syncthreads();
  int i0 = blockIdx.x * CHUNK;
  int i1 = min(e, i0 + CHUNK);
  for (int i = i0 + threadIdx.x; i < i1; i += 512)
    atomicAdd(&cnt[dst[i] >> 8], 1);
  __syncthreads();
  int c = cnt[threadIdx.x];
  if (c > 0) atomicAdd(&ghist[threadIdx.x], c);
}

// exclusive scan of ghist -> bstart (== global rowptr at bucket starts); gcursor = bstart
__global__ __launch_bounds__(512) void k_bscan(const int* __restrict__ ghist,
                                               int* __restrict__ bstart,
                                               int* __restrict__ gcursor) {
  __shared__ int s[NBKT];
  int v = ghist[threadIdx.x];
  s[threadIdx.x] = v;
  __syncthreads();
#pragma unroll
  for (int off = 1; off < NBKT; off <<= 1) {
    int t = (threadIdx.x >= off) ? s[threadIdx.x - off] : 0;
    __syncthreads();
    s[threadIdx.x] += t;
    __syncthreads();
  }
  int ex = s[threadIdx.x] - v;
  bstart[threadIdx.x] = ex;
  gcursor[threadIdx.x] = ex;
}

__global__ __launch_bounds__(512) void k_passA(const int* __restrict__ src,
                                               const int* __restrict__ dst,
                                               int* __restrict__ gcursor,
                                               unsigned* __restrict__ staged, int e) {
  __shared__ int cnt[NBKT];
  __shared__ int base[NBKT];
  cnt[threadIdx.x] = 0;
  __syncthreads();
  int i0 = blockIdx.x * CHUNK;
  int i1 = min(e, i0 + CHUNK);
  for (int i = i0 + threadIdx.x; i < i1; i += 512)
    atomicAdd(&cnt[dst[i] >> 8], 1);
  __syncthreads();
  int c = cnt[threadIdx.x];
  base[threadIdx.x] = (c > 0) ? atomicAdd(&gcursor[threadIdx.x], c) : 0;
  cnt[threadIdx.x] = 0;  // reuse as local cursor
  __syncthreads();
  for (int i = i0 + threadIdx.x; i < i1; i += 512) {
    int d = dst[i];
    int b = d >> 8;
    int lp = atomicAdd(&cnt[b], 1);
    staged[base[b] + lp] = ((unsigned)(d & 255) << 17) | (unsigned)src[i];
  }
}

// Fused per-bucket finalize: count -> dinv + rowptr (bstart[b] + local scan),
// place csr via LDS cursors, convert this bucket's x rows to pre-scaled bf16.
__global__ __launch_bounds__(256) void k_Bfused(
    const unsigned* __restrict__ staged, const int* __restrict__ bstart,
    const int* __restrict__ ghist, const float* __restrict__ x,
    float* __restrict__ dinv, int* __restrict__ rowptr, int* __restrict__ csr,
    ushort_t* __restrict__ xb, int n, int e) {
  __shared__ int cnt[256];
  __shared__ int s[256];
  __shared__ int cur[256];
  __shared__ float dinvL[256];
  const int tid = threadIdx.x;
  const int b = blockIdx.x;
  cnt[tid] = 0;
  __syncthreads();
  const int beg = bstart[b], end = beg + ghist[b];
  for (int i = beg + tid; i < end; i += 256)
    atomicAdd(&cnt[staged[i] >> 17], 1);
  __syncthreads();
  const int node = (b << 8) + tid;
  int v = (node < n) ? cnt[tid] : 0;
  float dv = rsqrtf((float)(v + 1));
  if (node < n) { dinv[node] = dv; }
  dinvL[tid] = dv;
  s[tid] = v;
  __syncthreads();
#pragma unroll
  for (int off = 1; off < 256; off <<= 1) {
    int t = (tid >= off) ? s[tid - off] : 0;
    __syncthreads();
    s[tid] += t;
    __syncthreads();
  }
  int rp = beg + s[tid] - v;  // global rowptr for this node
  if (node < n) rowptr[node] = rp;
  if (b == 0 && tid == 0) rowptr[n] = e;
  cur[tid] = rp;
  __syncthreads();
  // place edges
  for (int i = beg + tid; i < end; i += 256) {
    unsigned p = staged[i];
    int l = (int)(p >> 17);
    int sv = (int)(p & 0x1FFFFu);
    int pos = atomicAdd(&cur[l], 1);
    csr[pos] = sv;
  }
  // xconv for this bucket's nodes: 256 rows x 32 float4
  const int nb0 = b << 8;
  const int rows = min(256, n - nb0);
  const float4* xv = reinterpret_cast<const float4*>(x) + (size_t)nb0 * 32;
  u16x4* xo = reinterpret_cast<u16x4*>(xb) + (size_t)nb0 * 32;
  for (int j = tid; j < rows * 32; j += 256) {
    float sc = dinvL[j >> 5];
    float4 vv = xv[j];
    u16x4 o;
    o[0] = f2bf(vv.x * sc); o[1] = f2bf(vv.y * sc);
    o[2] = f2bf(vv.z * sc); o[3] = f2bf(vv.w * sc);
    xo[j] = o;
  }
}

// ---------------- gathers: one wave per node, lane-group row split ----------------
// item 0 = self row, items 1.. = csr edges. fp32 accumulate, shfl combine.

// layer 1: F=128, row=256B = 32 lanes x 8B; 2 items/step, 2-unroll
__global__ __launch_bounds__(256) void k_gather1(
    const ushort_t* __restrict__ t, ushort_t* __restrict__ outp,
    const int* __restrict__ rowptr, const int* __restrict__ csr, int n) {
  int wid = (blockIdx.x * blockDim.x + threadIdx.x) >> 6;
  int lane = threadIdx.x & 63;
  if (wid >= n) return;
  const int half = lane >> 5, sub = lane & 31;
  const int coff = sub * 4;
  int beg = rowptr[wid], end = rowptr[wid + 1];
  int nitems = end - beg + 1;
  float acc[4] = {};
  int i = 0;
  for (; i + 3 < nitems; i += 4) {
    int i0 = i + half, i1 = i + 2 + half;
    int r0 = (i0 == 0) ? wid : csr[beg + i0 - 1];
    int r1 = csr[beg + i1 - 1];
    u16x4 v0 = *reinterpret_cast<const u16x4*>(t + (size_t)r0 * IN_F + coff);
    u16x4 v1 = *reinterpret_cast<const u16x4*>(t + (size_t)r1 * IN_F + coff);
#pragma unroll
    for (int k = 0; k < 4; ++k) acc[k] += bf2f(v0[k]);
#pragma unroll
    for (int k = 0; k < 4; ++k) acc[k] += bf2f(v1[k]);
  }
  for (; i < nitems; i += 2) {
    int i0 = i + half;
    if (i0 < nitems) {
      int r0 = (i0 == 0) ? wid : csr[beg + i0 - 1];
      u16x4 v0 = *reinterpret_cast<const u16x4*>(t + (size_t)r0 * IN_F + coff);
#pragma unroll
      for (int k = 0; k < 4; ++k) acc[k] += bf2f(v0[k]);
    }
  }
#pragma unroll
  for (int k = 0; k < 4; ++k) acc[k] += __shfl_xor(acc[k], 32);
  if (half == 0) {
    u16x4 o;
#pragma unroll
    for (int k = 0; k < 4; ++k) o[k] = f2bf(acc[k]);
    *reinterpret_cast<u16x4*>(outp + (size_t)wid * IN_F + coff) = o;
  }
}

// layer 2: F=256, row=512B = 32 lanes x 16B; 2 items/step, 2-unroll
__global__ __launch_bounds__(256) void k_gather2(
    const ushort_t* __restrict__ t, ushort_t* __restrict__ outp,
    const int* __restrict__ rowptr, const int* __restrict__ csr,
    const float* __restrict__ dinv, const float* __restrict__ bias, int n) {
  int wid = (blockIdx.x * blockDim.x + threadIdx.x) >> 6;
  int lane = threadIdx.x & 63;
  if (wid >= n) return;
  const int half = lane >> 5, sub = lane & 31;
  const int coff = sub * 8;
  int beg = rowptr[wid], end = rowptr[wid + 1];
  int nitems = end - beg + 1;
  float acc[8] = {};
  int i = 0;
  for (; i + 3 < nitems; i += 4) {
    int i0 = i + half, i1 = i + 2 + half;
    int r0 = (i0 == 0) ? wid : csr[beg + i0 - 1];
    int r1 = csr[beg + i1 - 1];
    u16x8 v0 = *reinterpret_cast<const u16x8*>(t + (size_t)r0 * HID_F + coff);
    u16x8 v1 = *reinterpret_cast<const u16x8*>(t + (size_t)r1 * HID_F + coff);
#pragma unroll
    for (int k = 0; k < 8; ++k) acc[k] += bf2f(v0[k]);
#pragma unroll
    for (int k = 0; k < 8; ++k) acc[k] += bf2f(v1[k]);
  }
  for (; i < nitems; i += 2) {
    int i0 = i + half;
    if (i0 < nitems) {
      int r0 = (i0 == 0) ? wid : csr[beg + i0 - 1];
      u16x8 v0 = *reinterpret_cast<const u16x8*>(t + (size_t)r0 * HID_F + coff);
#pragma unroll
      for (int k = 0; k < 8; ++k) acc[k] += bf2f(v0[k]);
    }
  }
#pragma unroll
  for (int k = 0; k < 8; ++k) acc[k] += __shfl_xor(acc[k], 32);
  if (half == 0) {
    float s = dinv[wid];
    u16x8 o;
#pragma unroll
    for (int k = 0; k < 8; ++k) o[k] = f2bf(fmaxf(fmaf(acc[k], s, bias[coff + k]), 0.f));
    *reinterpret_cast<u16x8*>(outp + (size_t)wid * HID_F + coff) = o;
  }
}

// layer 3: F=64, row=128B = 16 lanes x 8B; 4 items/step; bias + L2-normalize
__global__ __launch_bounds__(256) void k_gather3(
    const ushort_t* __restrict__ t, float* __restrict__ outp,
    const int* __restrict__ rowptr, const int* __restrict__ csr,
    const float* __restrict__ dinv, const float* __restrict__ b3, int n) {
  int wid = (blockIdx.x * blockDim.x + threadIdx.x) >> 6;
  int lane = threadIdx.x & 63;
  if (wid >= n) return;
  const int q = lane >> 4, sub = lane & 15;
  const int coff = sub * 4;
  int beg = rowptr[wid], end = rowptr[wid + 1];
  int nitems = end - beg + 1;
  float acc[4] = {};
  for (int i = 0; i < nitems; i += 4) {
    int i0 = i + q;
    if (i0 < nitems) {
      int r0 = (i0 == 0) ? wid : csr[beg + i0 - 1];
      u16x4 v0 = *reinterpret_cast<const u16x4*>(t + (size_t)r0 * EMB_F + coff);
#pragma unroll
      for (int k = 0; k < 4; ++k) acc[k] += bf2f(v0[k]);
    }
  }
#pragma unroll
  for (int k = 0; k < 4; ++k) acc[k] += __shfl_xor(acc[k], 16);
#pragma unroll
  for (int k = 0; k < 4; ++k) acc[k] += __shfl_xor(acc[k], 32);
  float s = dinv[wid];
  float v[4], ss = 0.f;
#pragma unroll
  for (int k = 0; k < 4; ++k) {
    v[k] = fmaf(acc[k], s, b3[coff + k]);
    ss = fmaf(v[k], v[k], ss);
  }
#pragma unroll
  for (int off = 8; off > 0; off >>= 1) ss += __shfl_xor(ss, off);
  float inv = 1.0f / fmaxf(sqrtf(ss), 1e-12f);
  if (lane < 16) {
    float4 o = make_float4(v[0] * inv, v[1] * inv, v[2] * inv, v[3] * inv);
    *reinterpret_cast<float4*>(outp + (size_t)wid * EMB_F + coff) = o;
  }
}

// ---------------- block GEMM, LDS A-staging (64 rows x 256 cols / block) ----------------
// C[M][256] = dinv[row] * (A[M][K] @ Wt[256][K]^T) (+bias,relu). 4 waves;
// wave w computes cols [w*64, w*64+64). A staged once in LDS with chunk-XOR
// swizzle (chunk ^= row&7, 16B chunks), same involution on read.
// mfma_f32_16x16x32_bf16; C/D: col=lane&15, row=(lane>>4)*4+reg (m89-verified).

template<int K, bool RELU>
__global__ __launch_bounds__(256) void k_gemm_big(
    const ushort_t* __restrict__ A, const ushort_t* __restrict__ Wt,
    ushort_t* __restrict__ C, const float* __restrict__ dinv,
    const float* __restrict__ bias, int M) {
  __shared__ ushort_t As[64 * K];
  const int tid = threadIdx.x;
  const int lane = tid & 63;
  const int w = tid >> 6;
  const int mbase = blockIdx.x * 64;

  constexpr int CH = K / 8;  // 16B chunks per row
  for (int i = tid; i < 64 * CH; i += 256) {
    int row = i / CH, c = i - row * CH;
    int g = mbase + row;
    if (g >= M) g = M - 1;  // clamp; stores guarded
    u16x8 v = *reinterpret_cast<const u16x8*>(A + (size_t)g * K + c * 8);
    *reinterpret_cast<u16x8*>(&As[row * K + ((c ^ (row & 7)) << 3)]) = v;
  }
  __syncthreads();

  const int lrow = lane & 15;
  const int lk = (lane >> 4) * 8;
  const int nbase = w * 64;
  f32x4 acc[4][4] = {};

#pragma unroll
  for (int k0 = 0; k0 < K; k0 += 32) {
    bf16x8 a[4], b[4];
    const int cbase = (k0 >> 3) + (lane >> 4);
#pragma unroll
    for (int i = 0; i < 4; ++i) {
      int ri = i * 16 + lrow;
      a[i] = *reinterpret_cast<const bf16x8*>(&As[ri * K + ((cbase ^ (ri & 7)) << 3)]);
    }
#pragma unroll
    for (int n = 0; n < 4; ++n)
      b[n] = *reinterpret_cast<const bf16x8*>(Wt + (size_t)(nbase + n * 16 + lrow) * K + k0 + lk);
#pragma unroll
    for (int i = 0; i < 4; ++i)
#pragma unroll
      for (int n = 0; n < 4; ++n)
        acc[i][n] = __builtin_amdgcn_mfma_f32_16x16x32_bf16(a[i], b[n], acc[i][n], 0, 0, 0);
  }

#pragma unroll
  for (int i = 0; i < 4; ++i) {
    int growb = mbase + i * 16 + (lane >> 4) * 4;
#pragma unroll
    for (int r = 0; r < 4; ++r) {
      int grow = growb + r;
      if (grow >= M) continue;
      float s = dinv[grow];
#pragma unroll
      for (int n = 0; n < 4; ++n) {
        int gcol = nbase + n * 16 + (lane & 15);
        float v = acc[i][n][r] * s;
        if (RELU) v = fmaxf(v + bias[gcol], 0.f);
        C[(size_t)grow * HID_F + gcol] = f2bf(v);
      }
    }
  }
}

// ---------------- LDS-free wave GEMM (layer 3: NT=1, A read once) ----------------

template<int K, bool RELU>
__global__ __launch_bounds__(256) void k_mfma_gemm(
    const ushort_t* __restrict__ A, const ushort_t* __restrict__ Wt,
    ushort_t* __restrict__ C,
    const float* __restrict__ dinv, const float* __restrict__ bias,
    int M, int NT /* N/64 */) {
  int w = blockIdx.x * 4 + (threadIdx.x >> 6);
  int lane = threadIdx.x & 63;
  int mt = w / NT, nt = w - mt * NT;
  int mbase = mt * 64, nbase = nt * 64;
  if (mbase >= M) return;
  const int lrow = lane & 15;
  const int lk = (lane >> 4) * 8;
  const int N = NT * 64;

  int rows[4];
#pragma unroll
  for (int i = 0; i < 4; ++i) {
    int r = mbase + i * 16 + lrow;
    rows[i] = (r < M) ? r : (M - 1);  // clamp loads; stores guarded
  }

  f32x4 acc[4][4] = {};

#pragma unroll 2
  for (int k0 = 0; k0 < K; k0 += 32) {
    bf16x8 a[4], b[4];
#pragma unroll
    for (int i = 0; i < 4; ++i)
      a[i] = *reinterpret_cast<const bf16x8*>(A + (size_t)rows[i] * K + k0 + lk);
#pragma unroll
    for (int n = 0; n < 4; ++n)
      b[n] = *reinterpret_cast<const bf16x8*>(Wt + (size_t)(nbase + n * 16 + lrow) * K + k0 + lk);
#pragma unroll
    for (int i = 0; i < 4; ++i)
#pragma unroll
      for (int n = 0; n < 4; ++n)
        acc[i][n] = __builtin_amdgcn_mfma_f32_16x16x32_bf16(a[i], b[n], acc[i][n], 0, 0, 0);
  }

#pragma unroll
  for (int i = 0; i < 4; ++i) {
    int growb = mbase + i * 16 + (lane >> 4) * 4;
#pragma unroll
    for (int r = 0; r < 4; ++r) {
      int grow = growb + r;
      if (grow >= M) continue;
      float s = dinv[grow];
#pragma unroll
      for (int n = 0; n < 4; ++n) {
        int gcol = nbase + n * 16 + (lane & 15);
        float v = acc[i][n][r] * s;
        if (RELU) v = fmaxf(v + bias[gcol], 0.f);
        C[(size_t)grow * N + gcol] = f2bf(v);
      }
    }
  }
}

// ---------------- launch ----------------

extern "C" void kernel_launch(void* const* d_in, const int* in_sizes, int n_in,
                              void* d_out, int out_size, void* d_ws, size_t ws_size,
                              hipStream_t stream) {
  const float* x  = (const float*)d_in[0];
  const int*   ei = (const int*)d_in[1];
  const float* W1 = (const float*)d_in[2];
  const float* b1 = (const float*)d_in[3];
  const float* W2 = (const float*)d_in[4];
  const float* b2 = (const float*)d_in[5];
  const float* W3 = (const float*)d_in[6];
  const float* b3 = (const float*)d_in[7];
  const int N = in_sizes[0] / IN_F;
  const int E = in_sizes[1] / 2;
  const int* src = ei;
  const int* dst = ei + E;

  char* m = (char*)d_ws;
  auto alloc = [&](size_t bytes) { char* p = m; m += (bytes + 255) & ~(size_t)255; return p; };
  ushort_t* U1  = (ushort_t*)alloc((size_t)N * HID_F * 2);  // N x 256 bf16
  ushort_t* U2  = (ushort_t*)alloc((size_t)N * HID_F * 2);
  ushort_t* W1t = (ushort_t*)alloc((size_t)IN_F * HID_F * 2);
  ushort_t* W2t = (ushort_t*)alloc((size_t)HID_F * HID_F * 2);
  ushort_t* W3t = (ushort_t*)alloc((size_t)HID_F * EMB_F * 2);
  float*    dinv    = (float*)alloc((size_t)N * 4);
  int*      rowptr  = (int*)alloc((size_t)(N + 1) * 4);
  int*      ghist   = (int*)alloc(NBKT * 4);
  int*      bstart  = (int*)alloc(NBKT * 4);
  int*      gcursor = (int*)alloc(NBKT * 4);
  unsigned* staged  = (unsigned*)alloc((size_t)E * 4);
  int*      csr     = (int*)alloc((size_t)E * 4);
  float*    out     = (float*)d_out;

  const int nb = (N + 255) / 256;        // buckets (<= NBKT)
  const int echunks = (E + CHUNK - 1) / CHUNK;
  constexpr int SETUP_W = IN_F * HID_F + HID_F * HID_F + HID_F * EMB_F + NBKT;

  // weights -> bf16 transposed; ghist = 0
  k_setup<<<(SETUP_W + 255) / 256, 256, 0, stream>>>(W1, W2, W3, W1t, W2t, W3t, ghist);

  // bucketed CSR build
  k_hist  <<<echunks, 512, 0, stream>>>(dst, ghist, E);
  k_bscan <<<1, NBKT, 0, stream>>>(ghist, bstart, gcursor);
  k_passA <<<echunks, 512, 0, stream>>>(src, dst, gcursor, staged, E);

  // fused: dinv + rowptr + csr placement + xb = bf16(x * dinv)  (xb = U2 lower half)
  ushort_t* xb = U2;
  k_Bfused<<<nb, 256, 0, stream>>>(staged, bstart, ghist, x, dinv, rowptr, csr, xb, N, E);

  const int gblocks = (N + 3) / 4;  // gathers: 4 waves per block, 1 node per wave
  const int MT = (N + 63) / 64;

  // layer 1: gather xb -> aggX (U2 upper half); LDS-staged GEMM 128->256 -> h1
  ushort_t* aggX = U2 + (size_t)N * IN_F;
  k_gather1<<<gblocks, 256, 0, stream>>>(xb, aggX, rowptr, csr, N);
  ushort_t* h1 = U1;
  k_gemm_big<IN_F, true><<<MT, 256, 0, stream>>>(aggX, W1t, h1, dinv, b1, N);

  // layer 2: LDS-staged GEMM 256->256 (dinv row) -> t2 (U2; xb/aggX dead); gather -> h2
  ushort_t* t2 = U2;
  k_gemm_big<HID_F, false><<<MT, 256, 0, stream>>>(h1, W2t, t2, dinv, nullptr, N);
  ushort_t* h2 = U1;
  k_gather2<<<gblocks, 256, 0, stream>>>(t2, h2, rowptr, csr, dinv, b2, N);

  // layer 3: GEMM 256->64 (dinv row) -> t3; gather (+dinv, b3) + L2-normalize -> out
  ushort_t* t3 = U2;
  k_mfma_gemm<HID_F, false><<<(MT * (EMB_F / 64) + 3) / 4, 256, 0, stream>>>(
      h2, W3t, t3, dinv, nullptr, N, EMB_F / 64);
  k_gather3<<<gblocks, 256, 0, stream>>>(t3, out, rowptr, csr, dinv, b3, N);
}